// Round 8
// baseline (143.814 us; speedup 1.0000x reference)
//
#include <hip/hip_runtime.h>

// B=2048, T=8192, fp32 in, scalar fp32 out.
// d_in[0]=target_angle [B,T], d_in[1]=target_class [B,3],
// d_in[2]=pred_angle [B,T], d_in[3]=pred_class [B,3]
//
// R6 wma shape (2048 blocks, 4 one-shot grid-sweep chunks, nt loads) with
// the finalize FUSED via last-block-done: blocks write partials, bump a
// device-scope counter; the last block re-reduces all partials in fixed
// index order (deterministic) plus the class SSE, and writes the scalar.
// Counter is zeroed by hipMemsetAsync every call (graph-capture safe).

#define NTHREADS 256
#define CHUNKS 4

typedef float f32x4 __attribute__((ext_vector_type(4)));

__global__ __launch_bounds__(NTHREADS) void wma_fused_kernel(
    const float* __restrict__ ta, const float* __restrict__ pa,
    const float* __restrict__ tc, const float* __restrict__ pc,
    float* __restrict__ partial, unsigned int* __restrict__ counter,
    float* __restrict__ out, int T, int nClass)
{
    const int t = threadIdx.x;
    const int lane = t & 63;
    const long span = (long)gridDim.x * NTHREADS * 8;   // elements per sweep
    const long base = ((long)blockIdx.x * NTHREADS + t) * 8;
    const int col = (int)(base % T);  // span % T == 0 -> same col every chunk

    // ---- issue all main loads up-front (16 x global_load_dwordx4 nt) ----
    f32x4 A[CHUNKS][2], P[CHUNKS][2];
#pragma unroll
    for (int c = 0; c < CHUNKS; ++c) {
        const float* tap = ta + base + (long)c * span;
        const float* pap = pa + base + (long)c * span;
        A[c][0] = __builtin_nontemporal_load((const f32x4*)tap);
        A[c][1] = __builtin_nontemporal_load((const f32x4*)tap + 1);
        P[c][0] = __builtin_nontemporal_load((const f32x4*)pap);
        P[c][1] = __builtin_nontemporal_load((const f32x4*)pap + 1);
    }

    // ---- edge-lane halo loads (col>0 implies col>=2; col+8<T implies +9<T) ----
    float em1[CHUNKS], em2[CHUNKS], ep8[CHUNKS], ep9[CHUNKS];
#pragma unroll
    for (int c = 0; c < CHUNKS; ++c) { em1[c] = em2[c] = ep8[c] = ep9[c] = 0.0f; }
    if (lane == 0 && col > 0) {
#pragma unroll
        for (int c = 0; c < CHUNKS; ++c) {
            const long e = base + (long)c * span;
            em1[c] = ta[e - 1] - pa[e - 1];
            em2[c] = ta[e - 2] - pa[e - 2];
        }
    }
    if (lane == 63 && col + 8 < T) {
#pragma unroll
        for (int c = 0; c < CHUNKS; ++c) {
            const long e = base + (long)c * span;
            ep8[c] = ta[e + 8] - pa[e + 8];
            ep9[c] = ta[e + 9] - pa[e + 9];
        }
    }

    // ---- compute: 5-tap WMA of diff, squared, accumulated ----
    float acc = 0.0f;
#pragma unroll
    for (int c = 0; c < CHUNKS; ++c) {
        const float d0 = A[c][0].x - P[c][0].x;
        const float d1 = A[c][0].y - P[c][0].y;
        const float d2 = A[c][0].z - P[c][0].z;
        const float d3 = A[c][0].w - P[c][0].w;
        const float d4 = A[c][1].x - P[c][1].x;
        const float d5 = A[c][1].y - P[c][1].y;
        const float d6 = A[c][1].z - P[c][1].z;
        const float d7 = A[c][1].w - P[c][1].w;

        float dm2 = __shfl_up(d6, 1, 64);
        float dm1 = __shfl_up(d7, 1, 64);
        float dp8 = __shfl_down(d0, 1, 64);
        float dp9 = __shfl_down(d1, 1, 64);
        if (lane == 0)  { dm2 = em2[c]; dm1 = em1[c]; }
        if (lane == 63) { dp8 = ep8[c]; dp9 = ep9[c]; }

        float w;
        w = 0.05f*dm2 + 0.1f*dm1 + 0.7f*d0 + 0.1f*d1  + 0.05f*d2;  acc += w*w;
        w = 0.05f*dm1 + 0.1f*d0  + 0.7f*d1 + 0.1f*d2  + 0.05f*d3;  acc += w*w;
        w = 0.05f*d0  + 0.1f*d1  + 0.7f*d2 + 0.1f*d3  + 0.05f*d4;  acc += w*w;
        w = 0.05f*d1  + 0.1f*d2  + 0.7f*d3 + 0.1f*d4  + 0.05f*d5;  acc += w*w;
        w = 0.05f*d2  + 0.1f*d3  + 0.7f*d4 + 0.1f*d5  + 0.05f*d6;  acc += w*w;
        w = 0.05f*d3  + 0.1f*d4  + 0.7f*d5 + 0.1f*d6  + 0.05f*d7;  acc += w*w;
        w = 0.05f*d4  + 0.1f*d5  + 0.7f*d6 + 0.1f*d7  + 0.05f*dp8; acc += w*w;
        w = 0.05f*d5  + 0.1f*d6  + 0.7f*d7 + 0.1f*dp8 + 0.05f*dp9; acc += w*w;
    }

    // ---- block reduce ----
#pragma unroll
    for (int off = 32; off; off >>= 1) acc += __shfl_down(acc, off, 64);

    __shared__ float wsum[NTHREADS / 64];
    __shared__ bool isLast;
    if ((t & 63) == 0) wsum[t >> 6] = acc;
    __syncthreads();
    if (t == 0) {
        float b = 0.0f;
#pragma unroll
        for (int i = 0; i < NTHREADS / 64; ++i) b += wsum[i];
        partial[blockIdx.x] = b;
        __threadfence();   // make partial visible device-wide before count
        const unsigned int done = atomicAdd(counter, 1u);
        isLast = (done == gridDim.x - 1);
    }
    __syncthreads();
    if (!isLast) return;

    // ---- last block: deterministic fixed-order reduce + class SSE ----
    __threadfence();   // acquire: all partials visible
    const int grid = gridDim.x;

    float sa = 0.0f;
    for (int i = t; i < grid; i += NTHREADS) sa += partial[i];

    float sc = 0.0f;
    for (int i = t; i < nClass; i += NTHREADS) {
        const float d = tc[i] - pc[i];
        sc += d * d;
    }

#pragma unroll
    for (int off = 32; off; off >>= 1) {
        sa += __shfl_down(sa, off, 64);
        sc += __shfl_down(sc, off, 64);
    }

    __shared__ float ra[NTHREADS / 64], rc[NTHREADS / 64];
    if ((t & 63) == 0) { ra[t >> 6] = sa; rc[t >> 6] = sc; }
    __syncthreads();
    if (t == 0) {
        float a = 0.0f, c = 0.0f;
#pragma unroll
        for (int i = 0; i < NTHREADS / 64; ++i) { a += ra[i]; c += rc[i]; }
        out[0] = 0.8f * a + 0.2f * c;
    }
}

extern "C" void kernel_launch(void* const* d_in, const int* in_sizes, int n_in,
                              void* d_out, int out_size, void* d_ws, size_t ws_size,
                              hipStream_t stream)
{
    const float* ta = (const float*)d_in[0];  // target_angle [B,T]
    const float* tc = (const float*)d_in[1];  // target_class [B,3]
    const float* pa = (const float*)d_in[2];  // pred_angle  [B,T]
    const float* pc = (const float*)d_in[3];  // pred_class  [B,3]
    float* out = (float*)d_out;

    const int nAngle = in_sizes[0];           // B*T
    const int nClass = in_sizes[1];           // B*3
    const int T = 8192;
    const int grid = nAngle / (NTHREADS * 8 * CHUNKS);  // 2048

    float* partial = (float*)d_ws;                       // grid floats
    unsigned int* counter = (unsigned int*)((char*)d_ws + grid * sizeof(float));

    hipMemsetAsync(counter, 0, sizeof(unsigned int), stream);
    wma_fused_kernel<<<grid, NTHREADS, 0, stream>>>(
        ta, pa, tc, pc, partial, counter, out, T, nClass);
}

// Round 10
// 43.010 us; speedup vs baseline: 3.3437x; 3.3437x over previous
//
#include <hip/hip_runtime.h>

// B=2048, T=8192, fp32 in, scalar fp32 out.
// d_in[0]=target_angle [B,T], d_in[1]=target_class [B,3],
// d_in[2]=pred_angle [B,T], d_in[3]=pred_class [B,3]
//
// Proven-best configuration (R6): 2048 blocks; each thread owns 8 contiguous
// floats in each of 4 grid-sweep chunks; all 16 nt dwordx4 loads issued
// up-front; halo via wave shuffles, edge lanes patch from global; one reduce
// tail per 16 KB. Separate tiny finalize kernel (fusion attempts R8/R9 showed
// cross-XCD visibility is either 110us-slow via threadfence or incorrect via
// relaxed agent atomics -- two-kernel is the right structure).

#define NTHREADS 256
#define CHUNKS 4

typedef float f32x4 __attribute__((ext_vector_type(4)));

__global__ __launch_bounds__(NTHREADS) void wma_partial_kernel(
    const float* __restrict__ ta, const float* __restrict__ pa,
    float* __restrict__ partial, int T)
{
    const int t = threadIdx.x;
    const int lane = t & 63;
    const long span = (long)gridDim.x * NTHREADS * 8;   // elements per sweep
    const long base = ((long)blockIdx.x * NTHREADS + t) * 8;
    const int col = (int)(base % T);  // span % T == 0 -> same col every chunk

    // ---- issue all main loads up-front (16 x global_load_dwordx4 nt) ----
    f32x4 A[CHUNKS][2], P[CHUNKS][2];   // fully unrolled -> static indexing
#pragma unroll
    for (int c = 0; c < CHUNKS; ++c) {
        const float* tap = ta + base + (long)c * span;
        const float* pap = pa + base + (long)c * span;
        A[c][0] = __builtin_nontemporal_load((const f32x4*)tap);
        A[c][1] = __builtin_nontemporal_load((const f32x4*)tap + 1);
        P[c][0] = __builtin_nontemporal_load((const f32x4*)pap);
        P[c][1] = __builtin_nontemporal_load((const f32x4*)pap + 1);
    }

    // ---- edge-lane halo loads (col>0 implies col>=2; col+8<T implies +9<T) ----
    float em1[CHUNKS], em2[CHUNKS], ep8[CHUNKS], ep9[CHUNKS];
#pragma unroll
    for (int c = 0; c < CHUNKS; ++c) { em1[c] = em2[c] = ep8[c] = ep9[c] = 0.0f; }
    if (lane == 0 && col > 0) {
#pragma unroll
        for (int c = 0; c < CHUNKS; ++c) {
            const long e = base + (long)c * span;
            em1[c] = ta[e - 1] - pa[e - 1];
            em2[c] = ta[e - 2] - pa[e - 2];
        }
    }
    if (lane == 63 && col + 8 < T) {
#pragma unroll
        for (int c = 0; c < CHUNKS; ++c) {
            const long e = base + (long)c * span;
            ep8[c] = ta[e + 8] - pa[e + 8];
            ep9[c] = ta[e + 9] - pa[e + 9];
        }
    }

    // ---- compute: 5-tap WMA of diff, squared, accumulated ----
    float acc = 0.0f;
#pragma unroll
    for (int c = 0; c < CHUNKS; ++c) {
        const float d0 = A[c][0].x - P[c][0].x;
        const float d1 = A[c][0].y - P[c][0].y;
        const float d2 = A[c][0].z - P[c][0].z;
        const float d3 = A[c][0].w - P[c][0].w;
        const float d4 = A[c][1].x - P[c][1].x;
        const float d5 = A[c][1].y - P[c][1].y;
        const float d6 = A[c][1].z - P[c][1].z;
        const float d7 = A[c][1].w - P[c][1].w;

        float dm2 = __shfl_up(d6, 1, 64);
        float dm1 = __shfl_up(d7, 1, 64);
        float dp8 = __shfl_down(d0, 1, 64);
        float dp9 = __shfl_down(d1, 1, 64);
        if (lane == 0)  { dm2 = em2[c]; dm1 = em1[c]; }
        if (lane == 63) { dp8 = ep8[c]; dp9 = ep9[c]; }

        float w;
        w = 0.05f*dm2 + 0.1f*dm1 + 0.7f*d0 + 0.1f*d1  + 0.05f*d2;  acc += w*w;
        w = 0.05f*dm1 + 0.1f*d0  + 0.7f*d1 + 0.1f*d2  + 0.05f*d3;  acc += w*w;
        w = 0.05f*d0  + 0.1f*d1  + 0.7f*d2 + 0.1f*d3  + 0.05f*d4;  acc += w*w;
        w = 0.05f*d1  + 0.1f*d2  + 0.7f*d3 + 0.1f*d4  + 0.05f*d5;  acc += w*w;
        w = 0.05f*d2  + 0.1f*d3  + 0.7f*d4 + 0.1f*d5  + 0.05f*d6;  acc += w*w;
        w = 0.05f*d3  + 0.1f*d4  + 0.7f*d5 + 0.1f*d6  + 0.05f*d7;  acc += w*w;
        w = 0.05f*d4  + 0.1f*d5  + 0.7f*d6 + 0.1f*d7  + 0.05f*dp8; acc += w*w;
        w = 0.05f*d5  + 0.1f*d6  + 0.7f*d7 + 0.1f*dp8 + 0.05f*dp9; acc += w*w;
    }

    // ---- one wave reduce per 16 KB, then cross-wave via tiny LDS ----
#pragma unroll
    for (int off = 32; off; off >>= 1) acc += __shfl_down(acc, off, 64);

    __shared__ float wsum[NTHREADS / 64];
    if ((t & 63) == 0) wsum[t >> 6] = acc;
    __syncthreads();
    if (t == 0) {
        float b = 0.0f;
#pragma unroll
        for (int i = 0; i < NTHREADS / 64; ++i) b += wsum[i];
        partial[blockIdx.x] = b;
    }
}

__global__ __launch_bounds__(NTHREADS) void finalize_kernel(
    const float* __restrict__ partial, int nPartial,
    const float* __restrict__ tc, const float* __restrict__ pc, int nClass,
    float* __restrict__ out)
{
    const int t = threadIdx.x;

    float sa = 0.0f;
    for (int i = t; i < nPartial; i += NTHREADS) sa += partial[i];

    float sc = 0.0f;
    for (int i = t; i < nClass; i += NTHREADS) {
        const float d = tc[i] - pc[i];
        sc += d * d;
    }

#pragma unroll
    for (int off = 32; off; off >>= 1) {
        sa += __shfl_down(sa, off, 64);
        sc += __shfl_down(sc, off, 64);
    }

    __shared__ float ra[NTHREADS / 64], rc[NTHREADS / 64];
    if ((t & 63) == 0) { ra[t >> 6] = sa; rc[t >> 6] = sc; }
    __syncthreads();
    if (t == 0) {
        float a = 0.0f, c = 0.0f;
#pragma unroll
        for (int i = 0; i < NTHREADS / 64; ++i) { a += ra[i]; c += rc[i]; }
        out[0] = 0.8f * a + 0.2f * c;
    }
}

extern "C" void kernel_launch(void* const* d_in, const int* in_sizes, int n_in,
                              void* d_out, int out_size, void* d_ws, size_t ws_size,
                              hipStream_t stream)
{
    const float* ta = (const float*)d_in[0];  // target_angle [B,T]
    const float* tc = (const float*)d_in[1];  // target_class [B,3]
    const float* pa = (const float*)d_in[2];  // pred_angle  [B,T]
    const float* pc = (const float*)d_in[3];  // pred_class  [B,3]
    float* out = (float*)d_out;

    const int nAngle = in_sizes[0];           // B*T
    const int nClass = in_sizes[1];           // B*3
    const int T = 8192;
    const int grid = nAngle / (NTHREADS * 8 * CHUNKS);  // 2048

    float* partial = (float*)d_ws;            // grid floats (8 KB) < ws_size

    wma_partial_kernel<<<grid, NTHREADS, 0, stream>>>(ta, pa, partial, T);
    finalize_kernel<<<1, NTHREADS, 0, stream>>>(partial, grid, tc, pc, nClass, out);
}